// Round 13
// baseline (2285.957 us; speedup 1.0000x reference)
//
#include <hip/hip_runtime.h>
#include <cstdint>
#include <cstddef>
#include <cmath>

#define H  2048
#define BB 2048   // batch
#define TT 64     // time steps
#define NC 10     // classes
#define BK 64     // K-chunk per staging iter (8 x 16B chunks per row)

typedef __bf16 bf16;
typedef bf16  bf16x8 __attribute__((ext_vector_type(8)));
typedef float f32x4  __attribute__((ext_vector_type(4)));

// ---------------------------------------------------------------------------
// async global->LDS, 16B per lane. LDS dest is wave-uniform base + lane*16.
// ---------------------------------------------------------------------------
__device__ __forceinline__ void load_lds16(const void* g, void* l) {
    __builtin_amdgcn_global_load_lds(
        (__attribute__((address_space(1))) void*)(void*)g,
        (__attribute__((address_space(3))) void*)l,
        16, 0, 0);
}

// ---------------------------------------------------------------------------
// W_hh fp32 -> bf16, shuffled into MFMA-B-frag-major layout:
// subtile (n16, k32) = 16 n-rows x 32 k, 1024 B, at id = n16*64 + k32.
// Lane-slot l holds W[n16*16 + (l&15)][k32*32 + (l>>4)*8 .. +8] — exactly the
// v_mfma B-fragment, so a wave's B-frag load is ONE coalesced 1 KB segment.
// ---------------------------------------------------------------------------
__global__ void w_shuffle_kernel(const float* __restrict__ Whh,
                                 bf16* __restrict__ Wshuf) {
    int tid = blockIdx.x * blockDim.x + threadIdx.x;   // 0 .. H*H/8-1
    int sub = tid >> 6;          // subtile id
    int l   = tid & 63;          // dest lane slot
    int n16 = sub >> 6;          // 0..127
    int k32 = sub & 63;          // 0..63
    int n = n16 * 16 + (l & 15);
    int k = k32 * 32 + (l >> 4) * 8;
    const float* src = Whh + (size_t)n * H + k;
    bf16x8 o;
#pragma unroll
    for (int j = 0; j < 8; ++j) o[j] = (bf16)src[j];
    *(bf16x8*)(Wshuf + (size_t)tid * 8) = o;
}

// ---------------------------------------------------------------------------
// t = 0: S[b,i] = tanh(Whx[i]*x[b,0] + bh[i]).  One block per batch row.
// ---------------------------------------------------------------------------
__global__ void rnn_init(const float* __restrict__ x,     // [B, T]
                         const float* __restrict__ Whx,   // [H]
                         const float* __restrict__ bh,    // [H]
                         bf16* __restrict__ S) {          // [B, H]
    int b  = blockIdx.x;
    int i0 = threadIdx.x * 8;
    float xv = x[(size_t)b * TT];
    bf16x8 o;
#pragma unroll
    for (int j = 0; j < 8; ++j)
        o[j] = (bf16)tanhf(Whx[i0 + j] * xv + bh[i0 + j]);
    *(bf16x8*)(S + (size_t)b * H + i0) = o;
}

// ---------------------------------------------------------------------------
// One RNN time step. Round-13 = Round-10 (best, 1782 us) with the wave ->
// quadrant mapping changed from (qm{0,64} x qn{0,32}) to qm{0,32,64,96},
// every wave covering the full n=64 (wave tile 32m x 64n):
//   - A-frag LDS reads become DISJOINT across waves: 16 KB/iter instead of
//     32 KB (R10's qn-paired waves read identical A frags twice). LDS-pipe
//     traffic/iter drops 48 -> 32 KB; at the measured 85 B/cyc b128 rate
//     that moves the LDS floor from ~15 to ~10 us/step.
//   - B-frag redundancy rises 2x -> 4x, but B rides the L1/VMEM path
//     (same lines, L1-hot; L2->L1 volume unchanged) — redundancy moves from
//     the saturated pipe to the idle one (the same trade that won R9).
//   - acc[2][4] = 32 regs, B ping-pong 64 regs (same footprint as R12).
//
// Everything else proven & unchanged: grid 512 -> 2 blocks/CU (m114),
// bm-XCD map (S producer-consumer L2 locality), XOR-swizzled A staging
// (SQ_LDS_BANK_CONFLICT = 0), frag-major Wshuf (1 KB/wave coalesced B),
// single barrier per k-iter with 1-deep prefetch.
// ---------------------------------------------------------------------------
__launch_bounds__(256)
__global__ void rnn_step(const float* __restrict__ x,     // [B, T]
                         const float* __restrict__ Whx,   // [H]
                         const float* __restrict__ bh,    // [H]
                         const bf16*  __restrict__ Wshuf, // [H, H] frag-major
                         const bf16*  __restrict__ Sr,    // [B, H] read
                         bf16* __restrict__ Sw,           // [B, H] write
                         int t) {
    __shared__ __align__(16) bf16 As[2][128 * BK];  // 2 x 16 KB (S tile)

    const int tid  = threadIdx.x;
    const int w    = tid >> 6;          // wave 0..3
    const int lane = tid & 63;

    // XCD-aware mapping: XCD owns batch rows (S producer-consumer locality).
    const int xcd = blockIdx.x & 7;
    const int loc = blockIdx.x >> 3;              // 0..63
    const int bm0 = (xcd * 2 + (loc & 1)) * 128;  // batch-row tile origin
    const int bn0 = (loc >> 1) * 64;              // hidden-col tile origin

    const int qm   = w * 32;                     // wave m-quadrant (32 rows)
    const int lrow = lane & 15;
    const int quad = lane >> 4;

    const int s_r = tid >> 3;                    // staging row within 32-group
    const int s_l = tid & 7;                     // staging LDS chunk in row

    // B-frag source base: subtile id = n16*64 + k32; bf16 offset id*512+lane*8
    const int nb16 = bn0 >> 4;                   // n16 of fn=0 frag
    const bf16* wb = Wshuf + (size_t)lane * 8;

    auto stageA = [&](int b, int k0) {
#pragma unroll
        for (int i = 0; i < 4; ++i) {
            int r = i * 32 + s_r;                 // tile row 0..127
            int g = s_l ^ (r & 7);                // swizzled source chunk
            load_lds16(Sr + (size_t)(bm0 + r) * H + k0 + g * 8,
                       &As[b][(i * 256 + w * 64) * 8]);
        }
    };
    auto loadB = [&](bf16x8 (&B)[2][4], int k0) {
        const int kb32 = k0 >> 5;
#pragma unroll
        for (int kc = 0; kc < 2; ++kc)
#pragma unroll
            for (int fn = 0; fn < 4; ++fn)
                B[kc][fn] = *(const bf16x8*)(wb +
                    ((size_t)(nb16 + fn) * 64 + kb32 + kc) * 512);
    };

    f32x4 acc[2][4];
#pragma unroll
    for (int i = 0; i < 2; ++i)
#pragma unroll
        for (int j = 0; j < 4; ++j) acc[i][j] = (f32x4){0.f, 0.f, 0.f, 0.f};

    auto compute = [&](const bf16* Ab, bf16x8 (&B)[2][4]) {
#pragma unroll
        for (int kc = 0; kc < 2; ++kc) {
            bf16x8 af[2];
#pragma unroll
            for (int f = 0; f < 2; ++f) {
                int row = qm + f * 16 + lrow;
                int g   = kc * 4 + quad;
                int l   = g ^ (row & 7);
                af[f] = *(const bf16x8*)&Ab[(row * 8 + l) * 8];
            }
#pragma unroll
            for (int fm = 0; fm < 2; ++fm)
#pragma unroll
                for (int fn = 0; fn < 4; ++fn)
                    acc[fm][fn] = __builtin_amdgcn_mfma_f32_16x16x32_bf16(
                        af[fm], B[kc][fn], acc[fm][fn], 0, 0, 0);
        }
    };

    bf16x8 B0[2][4], B1[2][4];
    stageA(0, 0);
    loadB(B0, 0);

    for (int k0 = 0; k0 < H; k0 += 2 * BK) {
        __syncthreads();                          // drains A(k0) stage + B0
        if (k0 + BK < H) { loadB(B1, k0 + BK); stageA(1, k0 + BK); }
        compute(As[0], B0);

        __syncthreads();                          // drains A(k0+BK) + B1
        if (k0 + 2 * BK < H) { loadB(B0, k0 + 2 * BK); stageA(0, k0 + 2 * BK); }
        compute(As[1], B1);
    }

    // epilogue: z += Whx[i]*x[b,t] + bh[i]; tanh; store bf16.
    // C layout (16x16x32): col = lane&15, row = quad*4 + reg  [m89-verified]
#pragma unroll
    for (int fm = 0; fm < 2; ++fm) {
        int rb = bm0 + qm + fm * 16 + quad * 4;
        float xv[4];
#pragma unroll
        for (int r = 0; r < 4; ++r) xv[r] = x[(size_t)(rb + r) * TT + t];
#pragma unroll
        for (int fn = 0; fn < 4; ++fn) {
            int col = bn0 + fn * 16 + lrow;
            float wx = Whx[col], bb = bh[col];
#pragma unroll
            for (int r = 0; r < 4; ++r) {
                float z = acc[fm][fn][r] + wx * xv[r] + bb;
                Sw[(size_t)(rb + r) * H + col] = (bf16)tanhf(z);
            }
        }
    }
}

// ---------------------------------------------------------------------------
// out[b,c] = sum_h Why[h,c] * S[b,h] + bp[c]   (S = h_T^T, [B,H] bf16)
// one block per batch row
// ---------------------------------------------------------------------------
__global__ void out_proj(const bf16* __restrict__ S,
                         const float* __restrict__ Why,   // [H, C]
                         const float* __restrict__ bp,    // [C]
                         float* __restrict__ out) {       // [B, C]
    int b = blockIdx.x, tid = threadIdx.x;
    float p[NC];
#pragma unroll
    for (int c = 0; c < NC; ++c) p[c] = 0.f;
    for (int h = tid; h < H; h += 256) {
        float s = (float)S[(size_t)b * H + h];
        const float* wr = Why + h * NC;
#pragma unroll
        for (int c = 0; c < NC; ++c) p[c] += s * wr[c];
    }
    __shared__ float red[256 * NC];
#pragma unroll
    for (int c = 0; c < NC; ++c) red[tid * NC + c] = p[c];
    __syncthreads();
    for (int s = 128; s > 0; s >>= 1) {
        if (tid < s)
#pragma unroll
            for (int c = 0; c < NC; ++c) red[tid * NC + c] += red[(tid + s) * NC + c];
        __syncthreads();
    }
    if (tid < NC) out[(size_t)b * NC + tid] = red[tid] + bp[tid];
}

// ---------------------------------------------------------------------------
extern "C" void kernel_launch(void* const* d_in, const int* in_sizes, int n_in,
                              void* d_out, int out_size, void* d_ws, size_t ws_size,
                              hipStream_t stream) {
    const float* x   = (const float*)d_in[0];   // [B, T]
    const float* Whx = (const float*)d_in[1];   // [H, 1]
    const float* Whh = (const float*)d_in[2];   // [H, H]
    const float* Why = (const float*)d_in[3];   // [H, C]
    const float* bh  = (const float*)d_in[4];   // [H, 1]
    const float* bp  = (const float*)d_in[5];   // [C, 1]
    float* out = (float*)d_out;

    // workspace: Wshuf (8 MB) | S0 (8 MB) | S1 (8 MB)
    bf16* Wshuf = (bf16*)d_ws;
    bf16* S0 = (bf16*)((char*)d_ws + (size_t)8 * 1024 * 1024);
    bf16* S1 = (bf16*)((char*)d_ws + (size_t)16 * 1024 * 1024);

    hipLaunchKernelGGL(w_shuffle_kernel, dim3((H * H / 8) / 256), dim3(256),
                       0, stream, Whh, Wshuf);

    // t = 0 writes S1; step t reads (t&1 ? S1 : S0), writes the other.
    hipLaunchKernelGGL(rnn_init, dim3(BB), dim3(256), 0, stream, x, Whx, bh, S1);

    for (int t = 1; t < TT; ++t) {
        const bf16* Srd = (t & 1) ? S1 : S0;
        bf16*       Swr = (t & 1) ? S0 : S1;
        hipLaunchKernelGGL(rnn_step, dim3(512), dim3(256), 0, stream,
                           x, Whx, bh, Wshuf, Srd, Swr, t);
    }

    // t=63 (odd) wrote S0
    hipLaunchKernelGGL(out_proj, dim3(BB), dim3(256), 0, stream, S0, Why, bp, out);
}